// Round 10
// baseline (231.034 us; speedup 1.0000x reference)
//
#include <hip/hip_runtime.h>
#include <stdint.h>

#define NB   16
#define CD   256
#define HW   1024
#define NQ   16384
#define KCN  8192

typedef unsigned long long u64;
typedef unsigned short     u16;
using f32x4  = __attribute__((ext_vector_type(4))) float;
using bf16x8 = __attribute__((ext_vector_type(8))) __bf16;

// ---------------- workspace layout (~16.9 MB) ----------------
#define ZTB_OFF  0            // u16  [NQ][CD]    8 MB  (z transposed, bf16)
#define EMBB_OFF 8388608      // u16  [KCN][CD]   4 MB  (emb, bf16)
#define EH_OFF   12582912     // f32  [KCN]      32 KB  (||e||^2/2 + 1024)
#define CAND_OFF 12615680     // u64  [NQ][32]    4 MB  (8 splits x 2 halves x top-2)

static __device__ __forceinline__ unsigned bf16r(float x) {  // RNE fp32->bf16 bits
  unsigned u = __float_as_uint(x);
  return (u + 0x7fffu + ((u >> 16) & 1u)) >> 16;
}

static __device__ __forceinline__ u64 umin64(u64 a, u64 b) { return a < b ? a : b; }
static __device__ __forceinline__ u64 umax64(u64 a, u64 b) { return a < b ? b : a; }

// ---------------- kernel 1: merged prep (unchanged) ----------------
__global__ __launch_bounds__(256) void k_prep(const float* __restrict__ z,
                                              const float* __restrict__ emb,
                                              u16* __restrict__ zTb,
                                              u16* __restrict__ embB,
                                              float* __restrict__ eH) {
  const int bx = (int)blockIdx.x;
  if (bx < 1024) {
    __shared__ float tile[64][65];
    const int b   = bx >> 6;
    const int hwT = (bx >> 2) & 15;
    const int cT  = bx & 3;
    const int tx  = threadIdx.x & 63;
    const int ty  = threadIdx.x >> 6;
    const float* src = z + (size_t)(b * CD + cT * 64) * HW + hwT * 64;
#pragma unroll
    for (int i = 0; i < 16; ++i) {
      const int c_l = ty + 4 * i;
      tile[c_l][tx] = src[(size_t)c_l * HW + tx];
    }
    __syncthreads();
    const size_t dbase = (size_t)(b * HW + hwT * 64) * CD + cT * 64;
#pragma unroll
    for (int i = 0; i < 16; ++i) {
      const int hw_l = ty + 4 * i;
      zTb[dbase + (size_t)hw_l * CD + tx] = (u16)bf16r(tile[tx][hw_l]);
    }
  } else {
    const int wave = (bx - 1024) * 4 + ((int)threadIdx.x >> 6);  // 0..1023
    const int lane = threadIdx.x & 63;
#pragma unroll
    for (int it = 0; it < 8; ++it) {
      const int row = wave * 8 + it;
      const float4 v = *(const float4*)(emb + (size_t)row * CD + lane * 4);
      uint2 pk;
      pk.x = bf16r(v.x) | (bf16r(v.y) << 16);
      pk.y = bf16r(v.z) | (bf16r(v.w) << 16);
      *(uint2*)(embB + (size_t)row * CD + lane * 4) = pk;
      float s = v.x * v.x + v.y * v.y + v.z * v.z + v.w * v.w;
#pragma unroll
      for (int off = 32; off; off >>= 1) s += __shfl_xor(s, off, 64);
      if (lane == 0) eH[row] = 0.5f * s + 1024.0f;
    }
  }
}

// ---------------- kernel 2: R17 — NO LDS: B direct global->VGPR ---------------
// Plateau root-cause (re-derived with correct MFMA cost ~19.4 SIMD-cyc): every
// R9-R16 variant read B through LDS; per CU the LDS read port was ~4-5x
// oversubscribed vs the MFMA pipe -> MfmaUtil pinned 27-30% in ALL schedules.
// Fix per guide lesson "don't stage what cache-fits": B split = 512 KB,
// L2-resident. Load B frags STRAIGHT to VGPRs: addr (n0+l15)*512 + f*64 +
// quad*16 -> each instr reads 16 full 64B lines (100% util); frag k-mapping
// k = kc*64+ks*32+quad*8 identical to the LDS path (R11-proven MFMA pairing).
// No LDS, no barriers, no vmcnt ledger. Wave: Q=64 in regs (Af 128 VGPR),
// nh = 512-row half of split, 32 n-tiles of 16; double-buffered frag regs
// (8+8), prefetch 1 tile ahead; compiler inserts waits. acc[4] zeroed/tile;
// id = tile t (5 bits); per-q top-2, 16-lane butterfly, cand layout unchanged.
__global__ __launch_bounds__(256, 2) void k_argmin(const u16* __restrict__ zTb,
                                                   const u16* __restrict__ embB,
                                                   const float* __restrict__ eH,
                                                   u64* __restrict__ cand) {
  const int tid  = (int)threadIdx.x;
  const int w    = tid >> 6;
  const int lane = tid & 63;
  const int l15  = lane & 15, quad = lane >> 4;
  const int q0    = (int)(blockIdx.x >> 3) * 128;
  const int split = (int)(blockIdx.x & 7);
  const int wq0 = (w & 1) * 64;    // q-half
  const int nh  = w >> 1;          // n-half (bucket): 512 rows

  // ---- A fragments resident (128 VGPR):
  // Af[i][kc][ks][lane(quad,l15)] = A[q0+wq0+i*16+l15][kc*64+ks*32+quad*8 ..+7]
  bf16x8 Af[4][4][2];
  {
    const char* aB = (const char*)zTb + (size_t)(q0 + wq0 + l15) * 512 + quad * 16;
#pragma unroll
    for (int i = 0; i < 4; ++i)
#pragma unroll
      for (int kc = 0; kc < 4; ++kc)
#pragma unroll
        for (int ks = 0; ks < 2; ++ks)
          Af[i][kc][ks] = *(const bf16x8*)(aB + i * 8192 + kc * 128 + ks * 64);
  }

  // ---- B frag base: lane (quad,l15) reads row n0+l15, frag f: + f*64 + quad*16
  // (f = kc*2+ks -> k elems = kc*64 + ks*32 + quad*8, matches Af granules)
  const char* bP = (const char*)embB
                 + (size_t)(split * 1024 + nh * 512 + l15) * 512 + quad * 16;
  const float* ehP = eH + split * 1024 + nh * 512 + l15;

  f32x4 acc[4];
  float b1[16], b2[16];
  const float FMAX = __uint_as_float(0x7F7FFFFFu);
#pragma unroll
  for (int s = 0; s < 16; ++s) { b1[s] = FMAX; b2[s] = FMAX; }

#define LOADT(BUF, EHV, T)                                                     \
  do {                                                                         \
    const char* _p = bP + (size_t)(T) * 8192;                                  \
    BUF[0] = *(const bf16x8*)(_p + 0);                                         \
    BUF[1] = *(const bf16x8*)(_p + 64);                                        \
    BUF[2] = *(const bf16x8*)(_p + 128);                                       \
    BUF[3] = *(const bf16x8*)(_p + 192);                                       \
    BUF[4] = *(const bf16x8*)(_p + 256);                                       \
    BUF[5] = *(const bf16x8*)(_p + 320);                                       \
    BUF[6] = *(const bf16x8*)(_p + 384);                                       \
    BUF[7] = *(const bf16x8*)(_p + 448);                                       \
    EHV = ehP[(T) * 16];                                                       \
  } while (0)

// 32 MFMA (4 indep acc chains) + per-q single-value top-2 update, id = tile T
#define MFMA_EPI(BUF, EHV, T)                                                  \
  do {                                                                         \
    _Pragma("unroll")                                                          \
    for (int i = 0; i < 4; ++i) acc[i] = f32x4{0.f, 0.f, 0.f, 0.f};            \
    _Pragma("unroll")                                                          \
    for (int f = 0; f < 8; ++f)                                                \
      _Pragma("unroll")                                                        \
      for (int i = 0; i < 4; ++i)                                              \
        acc[i] = __builtin_amdgcn_mfma_f32_16x16x32_bf16(                      \
            Af[i][f >> 1][f & 1], BUF[f], acc[i], 0, 0, 0);                    \
    _Pragma("unroll")                                                          \
    for (int i = 0; i < 4; ++i)                                                \
      _Pragma("unroll")                                                        \
      for (int r = 0; r < 4; ++r) {                                            \
        const int s = i * 4 + r;                                               \
        const unsigned kb = (__float_as_uint((EHV) - acc[i][r]) & ~31u)        \
                            | (unsigned)(T);                                   \
        const float k = __uint_as_float(kb);                                   \
        b2[s] = fminf(fmaxf(k, b1[s]), b2[s]);                                 \
        b1[s] = fminf(k, b1[s]);                                               \
      }                                                                        \
  } while (0)

  bf16x8 bA[8], bB[8];
  float ehA, ehB;

  // ---- software pipeline: prefetch 1 tile ahead, unrolled x2 for static bufs
  LOADT(bA, ehA, 0);
  for (int tp = 0; tp < 15; ++tp) {
    const int t = 2 * tp;
    LOADT(bB, ehB, t + 1);
    MFMA_EPI(bA, ehA, t);
    LOADT(bA, ehA, t + 2);
    MFMA_EPI(bB, ehB, t + 1);
  }
  LOADT(bB, ehB, 31);
  MFMA_EPI(bA, ehA, 30);
  MFMA_EPI(bB, ehB, 31);
#undef LOADT
#undef MFMA_EPI

  // ---- per-wave: u64 butterfly top-2 merge over 16-lane groups, write cand
#pragma unroll
  for (int s = 0; s < 16; ++s) {
    u64 x1 = ((u64)__float_as_uint(b1[s]) << 32) | (unsigned)l15;
    u64 x2 = ((u64)__float_as_uint(b2[s]) << 32) | (unsigned)l15;
#pragma unroll
    for (int off = 1; off < 16; off <<= 1) {
      const u64 o1 = __shfl_xor(x1, off, 64);
      const u64 o2 = __shfl_xor(x2, off, 64);
      const u64 lo = umin64(x1, o1);
      const u64 hi = umax64(x1, o1);
      x1 = lo;
      x2 = umin64(hi, umin64(x2, o2));
    }
    if (l15 == 0) {
      const int i = s >> 2, r = s & 3;
      const int q = q0 + wq0 + i * 16 + quad * 4 + r;
      const unsigned kb1 = (unsigned)(x1 >> 32), kb2 = (unsigned)(x2 >> 32);
      // id = tile t (5 bits): n = split*1024 + nh*512 + t*16 + col
      const int n1 = split * 1024 + nh * 512 + (int)(kb1 & 31u) * 16
                     + (int)(x1 & 15);
      const int n2 = split * 1024 + nh * 512 + (int)(kb2 & 31u) * 16
                     + (int)(x2 & 15);
      cand[(size_t)q * 32 + split * 4 + nh * 2 + 0] = ((u64)kb1 << 32) | (unsigned)n1;
      cand[(size_t)q * 32 + split * 4 + nh * 2 + 1] = ((u64)kb2 << 32) | (unsigned)n2;
    }
  }
}

// ---------------- kernel 3: coalesced pick_out, 1024 threads (unchanged) ------
__global__ __launch_bounds__(1024) void k_pick_out(const float* __restrict__ z,
                                                   const float* __restrict__ emb,
                                                   const u64* __restrict__ cand,
                                                   float* __restrict__ out) {
  __shared__ float zs[64][256];   // 64 KB, reused for output staging
  const int t    = (int)threadIdx.x;
  const int lane = t & 63;
  const int wv   = t >> 6;        // 0..15
  const int l15  = t & 15;
  const int g    = t >> 4;        // 0..63 : query group
  const int q0b  = (int)blockIdx.x * 64;
  const int b    = q0b >> 10, hw0 = q0b & 1023;

  // ---- phase 0: wave wv stages channels wv*16..+15 (256B coalesced reads)
  {
    const float* zb = z + ((size_t)(b * CD + wv * 16)) * HW + hw0;
    const int sw = lane & 31;
#pragma unroll
    for (int i = 0; i < 16; ++i)
      zs[lane][(wv * 16 + i) ^ sw] = zb[(size_t)i * HW + lane];
  }
  __syncthreads();

  // ---- phase 1: top-4-of-32 select for query q = q0b + g
  const int q = q0b + g;
  const u64* cp = cand + (size_t)q * 32 + l15 * 2;
  const u64 v0 = cp[0], v1 = cp[1];
  u64 s0 = umin64(v0, v1), s1 = umax64(v0, v1), s2 = ~0ull, s3 = ~0ull;
#pragma unroll
  for (int off = 1; off < 16; off <<= 1) {
    const u64 b0 = __shfl_xor(s0, off, 64);
    const u64 b1 = __shfl_xor(s1, off, 64);
    const u64 b2 = __shfl_xor(s2, off, 64);
    const u64 b3 = __shfl_xor(s3, off, 64);
    const u64 c0 = umin64(s0, b0);
    const u64 c1 = umin64(umin64(s1, b1), umax64(s0, b0));
    const u64 c2 = umin64(umin64(s2, b2),
                          umin64(umax64(s1, b0), umax64(s0, b1)));
    const u64 c3 = umin64(umin64(umin64(s3, b3), umax64(s2, b0)),
                          umin64(umax64(s0, b2), umax64(s1, b1)));
    s0 = c0; s1 = c1; s2 = c2; s3 = c3;
  }
  const u64 sel[4] = {s0, s1, s2, s3};

  // ---- phase 2: fp64 rescore; lane handles channels c = j*16 + l15
  const int swq = g & 31;
  float zq[16];
#pragma unroll
  for (int j = 0; j < 16; ++j) zq[j] = zs[g][(j * 16 + l15) ^ swq];

  double bd = 1e300;
  int bi = 0x7fffffff;
  float keep[16];
#pragma unroll
  for (int j = 0; j < 16; ++j) keep[j] = 0.f;
#pragma unroll
  for (int c4 = 0; c4 < 4; ++c4) {
    const int idx = (int)(unsigned)(sel[c4] & 0xffffffffull);
    const float* er = emb + (size_t)idx * CD;
    float ev[16];
#pragma unroll
    for (int j = 0; j < 16; ++j) ev[j] = er[j * 16 + l15];
    double s = 0.0;
#pragma unroll
    for (int j = 0; j < 16; ++j) {
      const double d = (double)zq[j] - (double)ev[j];
      s += d * d;
    }
#pragma unroll
    for (int off = 1; off < 16; off <<= 1) s += __shfl_xor(s, off, 64);
    const bool better = (s < bd) || (s == bd && idx < bi);  // uniform in group
    if (better) {
      bd = s; bi = idx;
#pragma unroll
      for (int j = 0; j < 16; ++j) keep[j] = ev[j];
    }
  }

  // ---- phase 3: winner -> slab (reused), then coalesced 256B stores
  __syncthreads();   // all phase-2 slab reads complete
#pragma unroll
  for (int j = 0; j < 16; ++j) zs[g][(j * 16 + l15) ^ swq] = keep[j];
  __syncthreads();
  {
    float* ob = out + ((size_t)(b * CD + wv * 16)) * HW + hw0;
    const int sw = lane & 31;
#pragma unroll
    for (int i = 0; i < 16; ++i)
      ob[(size_t)i * HW + lane] = zs[lane][(wv * 16 + i) ^ sw];
  }
}

extern "C" void kernel_launch(void* const* d_in, const int* in_sizes, int n_in,
                              void* d_out, int out_size, void* d_ws, size_t ws_size,
                              hipStream_t stream) {
  const float* z   = (const float*)d_in[0];
  const float* emb = (const float*)d_in[1];
  float* out = (float*)d_out;

  char* ws = (char*)d_ws;
  u16*   zTb  = (u16*)(ws + ZTB_OFF);
  u16*   embB = (u16*)(ws + EMBB_OFF);
  float* eH   = (float*)(ws + EH_OFF);
  u64*   cand = (u64*)(ws + CAND_OFF);

  k_prep<<<1280, 256, 0, stream>>>(z, emb, zTb, embB, eH);
  k_argmin<<<1024, 256, 0, stream>>>(zTb, embB, eH, cand);
  k_pick_out<<<256, 1024, 0, stream>>>(z, emb, cand, out);
}

// Round 11
// 172.095 us; speedup vs baseline: 1.3425x; 1.3425x over previous
//
#include <hip/hip_runtime.h>
#include <stdint.h>

#define NB   16
#define CD   256
#define HW   1024
#define NQ   16384
#define KCN  8192

typedef unsigned long long u64;
typedef unsigned short     u16;
using f32x4  = __attribute__((ext_vector_type(4))) float;
using bf16x8 = __attribute__((ext_vector_type(8))) __bf16;

// ---------------- workspace layout (~16.9 MB) ----------------
#define ZTB_OFF  0            // u16  [NQ][CD]    8 MB  (z transposed, bf16)
#define EMBB_OFF 8388608      // u16  [KCN][CD]   4 MB  (emb, bf16)
#define EH_OFF   12582912     // f32  [KCN]      32 KB  (||e||^2/2 + 1024)
#define CAND_OFF 12615680     // u64  [NQ][32]    4 MB  (8 splits x 2 halves x top-2)

static __device__ __forceinline__ void gl_lds16(const void* g, void* l) {
  __builtin_amdgcn_global_load_lds(
      (const __attribute__((address_space(1))) void*)g,
      (__attribute__((address_space(3))) void*)l, 16, 0, 0);
}

static __device__ __forceinline__ unsigned bf16r(float x) {  // RNE fp32->bf16 bits
  unsigned u = __float_as_uint(x);
  return (u + 0x7fffu + ((u >> 16) & 1u)) >> 16;
}

static __device__ __forceinline__ u64 umin64(u64 a, u64 b) { return a < b ? a : b; }
static __device__ __forceinline__ u64 umax64(u64 a, u64 b) { return a < b ? b : a; }

// ---------------- kernel 1: merged prep — R18: 8B/lane transpose stores -------
// Old phase-2 stored 2B/lane (128B/instr). Now lane&15 covers 4 consecutive
// channels (ushort4, 8B/lane -> 512B/instr); rows via lane>>4 + i. LDS col
// reads tile[4a+jj][r]: word stride 260 %32 = 4 -> each bank 2 lanes (free).
__global__ __launch_bounds__(256) void k_prep(const float* __restrict__ z,
                                              const float* __restrict__ emb,
                                              u16* __restrict__ zTb,
                                              u16* __restrict__ embB,
                                              float* __restrict__ eH) {
  const int bx = (int)blockIdx.x;
  if (bx < 1024) {
    __shared__ float tile[64][65];
    const int b   = bx >> 6;
    const int hwT = (bx >> 2) & 15;
    const int cT  = bx & 3;
    const int tx  = threadIdx.x & 63;
    const int ty  = threadIdx.x >> 6;
    const float* src = z + (size_t)(b * CD + cT * 64) * HW + hwT * 64;
#pragma unroll
    for (int i = 0; i < 16; ++i) {
      const int c_l = ty + 4 * i;
      tile[c_l][tx] = src[(size_t)c_l * HW + tx];
    }
    __syncthreads();
    const size_t dbase = (size_t)(b * HW + hwT * 64) * CD + cT * 64;
    const int rsub = tx >> 4;        // 0..3
    const int cq   = (tx & 15) * 4;  // c_local quad base
#pragma unroll
    for (int i = 0; i < 4; ++i) {
      const int r = ty * 16 + i * 4 + rsub;   // hw_local
      ushort4 pk;
      pk.x = (u16)bf16r(tile[cq + 0][r]);
      pk.y = (u16)bf16r(tile[cq + 1][r]);
      pk.z = (u16)bf16r(tile[cq + 2][r]);
      pk.w = (u16)bf16r(tile[cq + 3][r]);
      *(ushort4*)(zTb + dbase + (size_t)r * CD + cq) = pk;
    }
  } else {
    const int wave = (bx - 1024) * 4 + ((int)threadIdx.x >> 6);  // 0..1023
    const int lane = threadIdx.x & 63;
#pragma unroll
    for (int it = 0; it < 8; ++it) {
      const int row = wave * 8 + it;
      const float4 v = *(const float4*)(emb + (size_t)row * CD + lane * 4);
      uint2 pk;
      pk.x = bf16r(v.x) | (bf16r(v.y) << 16);
      pk.y = bf16r(v.z) | (bf16r(v.w) << 16);
      *(uint2*)(embB + (size_t)row * CD + lane * 4) = pk;
      float s = v.x * v.x + v.y * v.y + v.z * v.z + v.w * v.w;
#pragma unroll
      for (int off = 32; off; off >>= 1) s += __shfl_xor(s, off, 64);
      if (lane == 0) eH[row] = 0.5f * s + 1024.0f;
    }
  }
}

// ---------------- kernel 2: R11 verbatim (best measured 94-97us, absmax 0) ----
// Structure ceiling reached for this geometry (~29-30% dense peak across 5
// schedule variants); R17 no-LDS failed on compiler reg-allocation (cap 128,
// Af not resident). Keep the proven best.

#define WAITV(N) asm volatile("s_waitcnt vmcnt(" #N ")" ::: "memory")
#define MEMFENCE() asm volatile("" ::: "memory")

__global__ __launch_bounds__(256, 2) void k_argmin(const u16* __restrict__ zTb,
                                                   const u16* __restrict__ embB,
                                                   const float* __restrict__ eH,
                                                   u64* __restrict__ cand) {
  __shared__ __align__(16) u16 Bs[4][128 * 64];   // 16 KB per ring slot

  const int tid  = (int)threadIdx.x;
  const int w    = tid >> 6;
  const int lane = tid & 63;
  const int l15  = lane & 15, quad = lane >> 4;
  const int q0    = (int)(blockIdx.x >> 3) * 128;
  const int split = (int)(blockIdx.x & 7);

  bf16x8 Af[2][4][2];
  {
    const char* aB = (const char*)zTb
                   + ((size_t)(q0 + w * 32 + l15) * CD + quad * 8) * 2;
#pragma unroll
    for (int i = 0; i < 2; ++i)
#pragma unroll
      for (int kc = 0; kc < 4; ++kc)
#pragma unroll
        for (int ks = 0; ks < 2; ++ks)
          Af[i][kc][ks] = *(const bf16x8*)(aB + i * 8192 + kc * 128 + ks * 64);
  }
  MEMFENCE();   // pin: A loads issue before any staging DMA (in-order vmcnt math)

  const char* bS = (const char*)embB + (size_t)split * (1024 * 512)
                 + (size_t)(w * 32 + (lane >> 3)) * 512
                 + (size_t)(((lane & 7) ^ (lane >> 3)) * 16);
  const int ldsW = w * 4096 + lane * 16;

#define STAGE(RING, NT_, KC_)                                                  \
  do {                                                                         \
    const char* _s = bS + (NT_) * 65536 + (KC_) * 128;                         \
    char* _d = (char*)Bs[RING] + ldsW;                                         \
    gl_lds16(_s,         _d);                                                  \
    gl_lds16(_s + 4096,  _d + 1024);                                           \
    gl_lds16(_s + 8192,  _d + 2048);                                           \
    gl_lds16(_s + 12288, _d + 3072);                                           \
  } while (0)

  const int bR0 = l15 * 128 + ((quad ^ (l15 & 7)) * 16);
  const int bR1 = bR0 ^ 64;

  f32x4 acc[2][8];
  float b1[8][2], b2[8][2];
  const float FMAX = __uint_as_float(0x7F7FFFFFu);
#pragma unroll
  for (int s = 0; s < 8; ++s) { b1[s][0] = b1[s][1] = FMAX; b2[s][0] = b2[s][1] = FMAX; }

  STAGE(0, 0, 0); MEMFENCE();
  STAGE(1, 0, 1); MEMFENCE();
  STAGE(2, 0, 2); MEMFENCE();

#define MFMA_INT(RING, KC_)                                                    \
  do {                                                                         \
    const char* _b = (const char*)Bs[RING];                                    \
    _Pragma("unroll")                                                          \
    for (int ks = 0; ks < 2; ++ks) {                                           \
      bf16x8 bfr[8];                                                           \
      const int _o = ks ? bR1 : bR0;                                           \
      _Pragma("unroll")                                                        \
      for (int j = 0; j < 8; ++j)                                              \
        bfr[j] = *(const bf16x8*)(_b + j * 2048 + _o);                         \
      __builtin_amdgcn_s_setprio(1);                                           \
      _Pragma("unroll")                                                        \
      for (int i = 0; i < 2; ++i)                                              \
        _Pragma("unroll")                                                      \
        for (int j = 0; j < 8; ++j)                                            \
          acc[i][j] = __builtin_amdgcn_mfma_f32_16x16x32_bf16(                 \
              Af[i][KC_][ks], bfr[j], acc[i][j], 0, 0, 0);                     \
      __builtin_amdgcn_s_setprio(0);                                           \
    }                                                                          \
  } while (0)

#define EPILOGUE(NT_)                                                          \
  do {                                                                         \
    _Pragma("unroll")                                                          \
    for (int i = 0; i < 2; ++i)                                                \
      _Pragma("unroll")                                                        \
      for (int r = 0; r < 4; ++r) {                                            \
        const int s = i * 4 + r;                                               \
        float kq[8];                                                           \
        _Pragma("unroll")                                                      \
        for (int j = 0; j < 8; ++j)                                            \
          kq[j] = __uint_as_float(                                             \
              (__float_as_uint(eh[j] - acc[i][j][r]) & ~63u)                   \
              | (unsigned)((NT_) * 8 + j));                                    \
        _Pragma("unroll")                                                      \
        for (int h = 0; h < 2; ++h) {                                          \
          const float k0 = kq[4 * h], k1 = kq[4 * h + 1];                      \
          const float k2 = kq[4 * h + 2], k3 = kq[4 * h + 3];                  \
          const float lo01 = fminf(k0, k1), hi01 = fmaxf(k0, k1);              \
          const float lo23 = fminf(k2, k3), hi23 = fmaxf(k2, k3);              \
          const float best = fminf(lo01, lo23);                                \
          const float sec  = fminf(fmaxf(lo01, lo23), fminf(hi01, hi23));      \
          b2[s][h] = fminf(fmaxf(best, b1[s][h]), fminf(sec, b2[s][h]));       \
          b1[s][h] = fminf(best, b1[s][h]);                                    \
        }                                                                      \
      }                                                                        \
  } while (0)

  float eh[8];

  for (int nt = 0; nt < 7; ++nt) {
    const int n0 = split * 1024 + nt * 128;
#pragma unroll
    for (int i = 0; i < 2; ++i)
#pragma unroll
      for (int j = 0; j < 8; ++j) acc[i][j] = f32x4{0.f, 0.f, 0.f, 0.f};

    WAITV(8); __builtin_amdgcn_s_barrier(); MEMFENCE();
    STAGE(3, nt, 3); MEMFENCE();
#pragma unroll
    for (int j = 0; j < 8; ++j) eh[j] = eH[n0 + j * 16 + l15];
    MEMFENCE();
    MFMA_INT(0, 0);
    WAITV(16); __builtin_amdgcn_s_barrier(); MEMFENCE();
    STAGE(0, nt + 1, 0); MEMFENCE();
    MFMA_INT(1, 1);
    WAITV(16); __builtin_amdgcn_s_barrier(); MEMFENCE();
    STAGE(1, nt + 1, 1); MEMFENCE();
    MFMA_INT(2, 2);
    WAITV(16); __builtin_amdgcn_s_barrier(); MEMFENCE();
    STAGE(2, nt + 1, 2); MEMFENCE();
    MFMA_INT(3, 3);

    EPILOGUE(nt);
  }

  {
    const int n0 = split * 1024 + 7 * 128;
#pragma unroll
    for (int i = 0; i < 2; ++i)
#pragma unroll
      for (int j = 0; j < 8; ++j) acc[i][j] = f32x4{0.f, 0.f, 0.f, 0.f};

    WAITV(8); __builtin_amdgcn_s_barrier(); MEMFENCE();
    STAGE(3, 7, 3); MEMFENCE();
#pragma unroll
    for (int j = 0; j < 8; ++j) eh[j] = eH[n0 + j * 16 + l15];
    MEMFENCE();
    MFMA_INT(0, 0);

    WAITV(16); __builtin_amdgcn_s_barrier(); MEMFENCE();
    MFMA_INT(1, 1);

    WAITV(12); __builtin_amdgcn_s_barrier(); MEMFENCE();
    MFMA_INT(2, 2);

    WAITV(8); __builtin_amdgcn_s_barrier(); MEMFENCE();
    MFMA_INT(3, 3);

    EPILOGUE(7);
  }
#undef STAGE
#undef MFMA_INT
#undef EPILOGUE

#pragma unroll
  for (int s = 0; s < 8; ++s) {
#pragma unroll
    for (int h = 0; h < 2; ++h) {
      u64 x1 = ((u64)__float_as_uint(b1[s][h]) << 32) | (unsigned)l15;
      u64 x2 = ((u64)__float_as_uint(b2[s][h]) << 32) | (unsigned)l15;
#pragma unroll
      for (int off = 1; off < 16; off <<= 1) {
        const u64 o1 = __shfl_xor(x1, off, 64);
        const u64 o2 = __shfl_xor(x2, off, 64);
        const u64 lo = umin64(x1, o1);
        const u64 hi = umax64(x1, o1);
        x1 = lo;
        x2 = umin64(hi, umin64(x2, o2));
      }
      if (l15 == 0) {
        const int i = s >> 2, r = s & 3;
        const int q = q0 + w * 32 + i * 16 + quad * 4 + r;
        const unsigned kb1 = (unsigned)(x1 >> 32), kb2 = (unsigned)(x2 >> 32);
        const int n1 = split * 1024 + (int)((kb1 >> 3) & 7) * 128
                       + (int)(kb1 & 7) * 16 + (int)(x1 & 15);
        const int n2 = split * 1024 + (int)((kb2 >> 3) & 7) * 128
                       + (int)(kb2 & 7) * 16 + (int)(x2 & 15);
        cand[(size_t)q * 32 + split * 4 + h * 2 + 0] = ((u64)kb1 << 32) | (unsigned)n1;
        cand[(size_t)q * 32 + split * 4 + h * 2 + 1] = ((u64)kb2 << 32) | (unsigned)n2;
      }
    }
  }
}

// ---------------- kernel 3: R18 — c-major slab, float2 both ways, slim regs ---
// zs[256][66] (c-major, pad 2): phase0/3 move float2 per lane (512B/instr).
// Rescore keeps only (bd, bi); winner row re-gathered from L2-hot emb after
// the loop (identical fp64 sum order -> bit-identical result). ~45 live VGPRs.
__global__ __launch_bounds__(1024) void k_pick_out(const float* __restrict__ z,
                                                   const float* __restrict__ emb,
                                                   const u64* __restrict__ cand,
                                                   float* __restrict__ out) {
  __shared__ float zs[256][66];   // 67.6 KB
  const int t    = (int)threadIdx.x;
  const int lane = t & 63;
  const int wv   = t >> 6;        // 0..15
  const int l15  = t & 15;
  const int g    = t >> 4;        // 0..63 : query group
  const int q0b  = (int)blockIdx.x * 64;
  const int b    = q0b >> 10, hw0 = q0b & 1023;

  // ---- phase 0: wave wv stages channels [wv*16, wv*16+16), float2 per lane
  {
    const int hw   = (lane & 31) * 2;
    const int csub = lane >> 5;     // 0..1
#pragma unroll
    for (int i = 0; i < 8; ++i) {
      const int c = wv * 16 + i * 2 + csub;
      const float2 v = *(const float2*)(z + ((size_t)(b * CD + c)) * HW + hw0 + hw);
      *(float2*)&zs[c][hw] = v;
    }
  }
  __syncthreads();

  // ---- phase 1: top-4-of-32 select for query q = q0b + g
  const int q = q0b + g;
  const u64* cp = cand + (size_t)q * 32 + l15 * 2;
  const u64 v0 = cp[0], v1 = cp[1];
  u64 s0 = umin64(v0, v1), s1 = umax64(v0, v1), s2 = ~0ull, s3 = ~0ull;
#pragma unroll
  for (int off = 1; off < 16; off <<= 1) {
    const u64 b0 = __shfl_xor(s0, off, 64);
    const u64 b1 = __shfl_xor(s1, off, 64);
    const u64 b2 = __shfl_xor(s2, off, 64);
    const u64 b3 = __shfl_xor(s3, off, 64);
    const u64 c0 = umin64(s0, b0);
    const u64 c1 = umin64(umin64(s1, b1), umax64(s0, b0));
    const u64 c2 = umin64(umin64(s2, b2),
                          umin64(umax64(s1, b0), umax64(s0, b1)));
    const u64 c3 = umin64(umin64(umin64(s3, b3), umax64(s2, b0)),
                          umin64(umax64(s0, b2), umax64(s1, b1)));
    s0 = c0; s1 = c1; s2 = c2; s3 = c3;
  }
  const u64 sel[4] = {s0, s1, s2, s3};

  // ---- phase 2: fp64 rescore; lane handles channels c = j*16 + l15
  float zq[16];
#pragma unroll
  for (int j = 0; j < 16; ++j) zq[j] = zs[j * 16 + l15][g];

  double bd = 1e300;
  int bi = 0x7fffffff;
#pragma unroll
  for (int c4 = 0; c4 < 4; ++c4) {
    const int idx = (int)(unsigned)(sel[c4] & 0xffffffffull);
    const float* er = emb + (size_t)idx * CD;
    double s = 0.0;
#pragma unroll
    for (int j = 0; j < 16; ++j) {
      const double d = (double)zq[j] - (double)er[j * 16 + l15];
      s += d * d;
    }
#pragma unroll
    for (int off = 1; off < 16; off <<= 1) s += __shfl_xor(s, off, 64);
    const bool better = (s < bd) || (s == bd && idx < bi);  // uniform in group
    if (better) { bd = s; bi = idx; }
  }

  // ---- phase 3: winner row -> slab (reused), then coalesced float2 stores
  __syncthreads();   // all phase-2 slab reads complete
  {
    const float* ew = emb + (size_t)bi * CD;
#pragma unroll
    for (int j = 0; j < 16; ++j) zs[j * 16 + l15][g] = ew[j * 16 + l15];
  }
  __syncthreads();
  {
    const int hw   = (lane & 31) * 2;
    const int csub = lane >> 5;
#pragma unroll
    for (int i = 0; i < 8; ++i) {
      const int c = wv * 16 + i * 2 + csub;
      const float2 v = *(const float2*)&zs[c][hw];
      *(float2*)(out + ((size_t)(b * CD + c)) * HW + hw0 + hw) = v;
    }
  }
}

extern "C" void kernel_launch(void* const* d_in, const int* in_sizes, int n_in,
                              void* d_out, int out_size, void* d_ws, size_t ws_size,
                              hipStream_t stream) {
  const float* z   = (const float*)d_in[0];
  const float* emb = (const float*)d_in[1];
  float* out = (float*)d_out;

  char* ws = (char*)d_ws;
  u16*   zTb  = (u16*)(ws + ZTB_OFF);
  u16*   embB = (u16*)(ws + EMBB_OFF);
  float* eH   = (float*)(ws + EH_OFF);
  u64*   cand = (u64*)(ws + CAND_OFF);

  k_prep<<<1280, 256, 0, stream>>>(z, emb, zTb, embB, eH);
  k_argmin<<<1024, 256, 0, stream>>>(zTb, embB, eH, cand);
  k_pick_out<<<256, 1024, 0, stream>>>(z, emb, cand, out);
}